// Round 11
// baseline (298.699 us; speedup 1.0000x reference)
//
#include <hip/hip_runtime.h>
#include <hip/hip_bf16.h>
#include <math.h>

typedef __bf16 bf16;
typedef bf16 bf16x8 __attribute__((ext_vector_type(8)));
typedef float f32x4 __attribute__((ext_vector_type(4)));
typedef unsigned short ushort_t;
typedef unsigned long long u64;

#define N_NODES 100000
#define N_EDGES 640000
#define DD 128
#define MAXDEG 64
#define STAT_SCALE 1048576.0

__device__ __forceinline__ float gelu_fast(float x) {
    float z2 = x * (1.595769122f + 0.071354816f * x * x);
    return x * __builtin_amdgcn_rcpf(1.0f + __expf(-z2));
}

__device__ __forceinline__ ushort_t bf16_bits(float x) {
    bf16 h = (bf16)x;
    return __builtin_bit_cast(ushort_t, h);
}

__device__ __forceinline__ float bits_to_f(ushort_t u) {
    return __uint_as_float(((unsigned)u) << 16);
}

__device__ __forceinline__ long long to_fixed(double x) {
    return (long long)(x * STAT_SCALE + (x >= 0.0 ? 0.5 : -0.5));
}

__device__ __forceinline__ void stats_atomic(float lsum, float lsq, float* red,
                                             u64* dsum, u64* dsq) {
    int tid = threadIdx.x;
    red[tid] = lsum; __syncthreads();
    for (int s = 128; s > 0; s >>= 1) { if (tid < s) red[tid] += red[tid + s]; __syncthreads(); }
    float bs = red[0]; __syncthreads();
    red[tid] = lsq; __syncthreads();
    for (int s = 128; s > 0; s >>= 1) { if (tid < s) red[tid] += red[tid + s]; __syncthreads(); }
    if (tid == 0) {
        atomicAdd(dsum, (u64)to_fixed((double)bs));
        atomicAdd(dsq,  (u64)to_fixed((double)red[0]));
    }
}

__device__ __forceinline__ void stats_decode(const u64* stats, double cnt,
                                             float* mu, float* rs) {
    long long ss = (long long)stats[0], sq = (long long)stats[1];
    double mu_d = ((double)ss / STAT_SCALE) / cnt;
    double var  = ((double)sq / STAT_SCALE) / cnt - mu_d * mu_d;
    *mu = (float)mu_d;
    *rs = (float)(1.0 / sqrt(var + 1e-5));
}

#define PACK8(dstp, a, b) { \
    ushort_t o_[8] = {bf16_bits(a.x), bf16_bits(a.y), bf16_bits(a.z), bf16_bits(a.w), \
                      bf16_bits(b.x), bf16_bits(b.y), bf16_bits(b.z), bf16_bits(b.w)}; \
    *(uint4*)(dstp) = *(const uint4*)o_; }

// ---------------- K0: parallel init of cnt + stats ---------------------------
__global__ __launch_bounds__(256) void k0_init(int* __restrict__ cnt,
                                               u64* __restrict__ stats)
{
    int i = blockIdx.x * 256 + threadIdx.x;
    if (i < N_NODES) cnt[i] = 0;
    if (i < 4) stats[i] = 0ull;
}

// ---------------- K1: hpre = bf16(nf @ W1 + b1) + stats1 ---------------------
#define K1_TILES 1563
__global__ __launch_bounds__(256) void k1_gemm1(
    const float* __restrict__ nf, const float* __restrict__ W1,
    const float* __restrict__ b1, ushort_t* __restrict__ hpre,
    u64* __restrict__ stats, int nblocks)
{
    __shared__ bf16 Ash[2][64 * 136];
    __shared__ float red[256];
    const int tid = threadIdx.x;
    const int lane = tid & 63;
    const int w = tid >> 6;
    const int l15 = lane & 15, l4 = lane >> 4;

    bf16x8 bfrag[4][2];
    #pragma unroll
    for (int s = 0; s < 4; ++s)
        #pragma unroll
        for (int t = 0; t < 2; ++t) {
            int n = w * 32 + t * 16 + l15;
            #pragma unroll
            for (int j = 0; j < 8; ++j)
                bfrag[s][t][j] = (bf16)W1[(s * 32 + l4 * 8 + j) * DD + n];
        }
    float4 bias4[2];
    bias4[0] = *(const float4*)&b1[w * 32 + l4 * 4];
    bias4[1] = *(const float4*)&b1[w * 32 + 16 + l4 * 4];

    float lsum = 0.f, lsq = 0.f;
    const int srow = tid >> 2;
    const int q = tid & 3;

    float4 efr[8];
    {
        int grow = min(blockIdx.x * 64 + srow, N_NODES - 1);
        const float4* p = (const float4*)&nf[(size_t)grow * DD + q * 32];
        #pragma unroll
        for (int u = 0; u < 8; ++u) efr[u] = p[u];
    }

    int buf = 0;
    for (int tile = blockIdx.x; tile < K1_TILES; tile += nblocks) {
        const int rbase = tile * 64;
        #pragma unroll
        for (int u = 0; u < 4; ++u)
            PACK8(&Ash[buf][srow * 136 + q * 32 + u * 8], efr[2 * u], efr[2 * u + 1]);
        __syncthreads();
        int nt = tile + nblocks;
        if (nt < K1_TILES) {
            int grow = min(nt * 64 + srow, N_NODES - 1);
            const float4* p = (const float4*)&nf[(size_t)grow * DD + q * 32];
            #pragma unroll
            for (int u = 0; u < 8; ++u) efr[u] = p[u];
        }
        f32x4 acc[4][2];
        #pragma unroll
        for (int r = 0; r < 4; ++r)
            #pragma unroll
            for (int t = 0; t < 2; ++t)
                acc[r][t] = (f32x4){0.f, 0.f, 0.f, 0.f};
        #pragma unroll
        for (int s = 0; s < 4; ++s)
            #pragma unroll
            for (int r = 0; r < 4; ++r) {
                bf16x8 a = *(const bf16x8*)&Ash[buf][(r * 16 + l15) * 136 + s * 32 + l4 * 8];
                acc[r][0] = __builtin_amdgcn_mfma_f32_16x16x32_bf16(bfrag[s][0], a, acc[r][0], 0, 0, 0);
                acc[r][1] = __builtin_amdgcn_mfma_f32_16x16x32_bf16(bfrag[s][1], a, acc[r][1], 0, 0, 0);
            }
        #pragma unroll
        for (int r = 0; r < 4; ++r) {
            int row = rbase + r * 16 + l15;
            if (row < N_NODES) {
                #pragma unroll
                for (int t = 0; t < 2; ++t) {
                    int col = w * 32 + t * 16 + l4 * 4;
                    ushort_t o[4];
                    #pragma unroll
                    for (int j = 0; j < 4; ++j) {
                        float v = acc[r][t][j] + bias4[t][j];
                        lsum += v; lsq += v * v;
                        o[j] = bf16_bits(v);
                    }
                    *(uint2*)&hpre[(size_t)row * DD + col] = *(const uint2*)o;
                }
            }
        }
        buf ^= 1;
    }
    stats_atomic(lsum, lsq, red, &stats[0], &stats[1]);
}

// ---------------- K2b: hh = bf16( gelu(LN(hpre)) @ W2_bot + b2 ) -------------
__global__ __launch_bounds__(256) void k2b_gemmh(
    const ushort_t* __restrict__ hpre, const float* __restrict__ W2,
    const float* __restrict__ b2, const u64* __restrict__ stats,
    ushort_t* __restrict__ hh, int nblocks)
{
    __shared__ bf16 Ash[2][64 * 136];
    float mu, rs;
    stats_decode(stats, (double)N_NODES * DD, &mu, &rs);

    const int tid = threadIdx.x;
    const int lane = tid & 63;
    const int w = tid >> 6;
    const int l15 = lane & 15, l4 = lane >> 4;

    bf16x8 bfrag[4][2];
    #pragma unroll
    for (int s = 0; s < 4; ++s)
        #pragma unroll
        for (int t = 0; t < 2; ++t) {
            int n = w * 32 + t * 16 + l15;
            #pragma unroll
            for (int j = 0; j < 8; ++j)
                bfrag[s][t][j] = (bf16)W2[(DD + s * 32 + l4 * 8 + j) * DD + n];
        }
    float4 bias4[2];
    bias4[0] = *(const float4*)&b2[w * 32 + l4 * 4];
    bias4[1] = *(const float4*)&b2[w * 32 + 16 + l4 * 4];

    const int srow = tid >> 2;
    const int q = tid & 3;

    uint4 hr[4];
    {
        int grow = min(blockIdx.x * 64 + srow, N_NODES - 1);
        const uint4* p = (const uint4*)&hpre[(size_t)grow * DD + q * 32];
        #pragma unroll
        for (int u = 0; u < 4; ++u) hr[u] = p[u];
    }

    int buf = 0;
    for (int tile = blockIdx.x; tile < K1_TILES; tile += nblocks) {
        const int rbase = tile * 64;
        #pragma unroll
        for (int u = 0; u < 4; ++u) {
            const ushort_t* in = (const ushort_t*)&hr[u];
            ushort_t o[8];
            #pragma unroll
            for (int j = 0; j < 8; ++j)
                o[j] = bf16_bits(gelu_fast((bits_to_f(in[j]) - mu) * rs));
            *(uint4*)&Ash[buf][srow * 136 + q * 32 + u * 8] = *(const uint4*)o;
        }
        __syncthreads();
        int nt = tile + nblocks;
        if (nt < K1_TILES) {
            int grow = min(nt * 64 + srow, N_NODES - 1);
            const uint4* p = (const uint4*)&hpre[(size_t)grow * DD + q * 32];
            #pragma unroll
            for (int u = 0; u < 4; ++u) hr[u] = p[u];
        }
        f32x4 acc[4][2];
        #pragma unroll
        for (int r = 0; r < 4; ++r)
            #pragma unroll
            for (int t = 0; t < 2; ++t)
                acc[r][t] = (f32x4){0.f, 0.f, 0.f, 0.f};
        #pragma unroll
        for (int s = 0; s < 4; ++s)
            #pragma unroll
            for (int r = 0; r < 4; ++r) {
                bf16x8 a = *(const bf16x8*)&Ash[buf][(r * 16 + l15) * 136 + s * 32 + l4 * 8];
                acc[r][0] = __builtin_amdgcn_mfma_f32_16x16x32_bf16(bfrag[s][0], a, acc[r][0], 0, 0, 0);
                acc[r][1] = __builtin_amdgcn_mfma_f32_16x16x32_bf16(bfrag[s][1], a, acc[r][1], 0, 0, 0);
            }
        #pragma unroll
        for (int r = 0; r < 4; ++r) {
            int row = rbase + r * 16 + l15;
            if (row < N_NODES) {
                #pragma unroll
                for (int t = 0; t < 2; ++t) {
                    int col = w * 32 + t * 16 + l4 * 4;
                    ushort_t o[4];
                    #pragma unroll
                    for (int j = 0; j < 4; ++j)
                        o[j] = bf16_bits(acc[r][t][j] + bias4[t][j]);
                    *(uint2*)&hh[(size_t)row * DD + col] = *(const uint2*)o;
                }
            }
        }
        buf ^= 1;
    }
}

// ---------------- K4: e0 = bf16( ef @ W2_top + hh[src] ) + stats2 ------------
#define K4_WTILES (N_EDGES / 16)

#define K4_LOAD_SRC(dst, t) { if ((t) < K4_WTILES) dst = eidx[(size_t)((t) * 16 + l15) * 2]; }

#define K4_LOAD_PANEL(raw, t) { if ((t) < K4_WTILES) { \
    const float* base_ = &ef[(size_t)((t) * 16 + l15) * DD + l4 * 8]; \
    raw##0 = *(const float4*)(base_);       raw##1 = *(const float4*)(base_ + 4); \
    raw##2 = *(const float4*)(base_ + 32);  raw##3 = *(const float4*)(base_ + 36); \
    raw##4 = *(const float4*)(base_ + 64);  raw##5 = *(const float4*)(base_ + 68); \
    raw##6 = *(const float4*)(base_ + 96);  raw##7 = *(const float4*)(base_ + 100); } }

#define K4_LOAD_HV(hv, srcreg, t) { if ((t) < K4_WTILES) { \
    const ushort_t* hb_ = &hh[(size_t)(srcreg) * DD + l4 * 4]; \
    hv[0] = *(const uint2*)(hb_);       hv[1] = *(const uint2*)(hb_ + 16); \
    hv[2] = *(const uint2*)(hb_ + 32);  hv[3] = *(const uint2*)(hb_ + 48); \
    hv[4] = *(const uint2*)(hb_ + 64);  hv[5] = *(const uint2*)(hb_ + 80); \
    hv[6] = *(const uint2*)(hb_ + 96);  hv[7] = *(const uint2*)(hb_ + 112); } }

#define K4_COMPUTE_STORE(t, raw, hv) { \
    f32x4 acc[8]; \
    _Pragma("unroll") \
    for (int tt = 0; tt < 8; ++tt) acc[tt] = (f32x4){0.f, 0.f, 0.f, 0.f}; \
    _Pragma("unroll") \
    for (int s = 0; s < 4; ++s) { \
        float4 ra_ = raw##_arr(2 * s), rb_ = raw##_arr(2 * s + 1); \
        ushort_t af_[8] = {bf16_bits(ra_.x), bf16_bits(ra_.y), bf16_bits(ra_.z), bf16_bits(ra_.w), \
                           bf16_bits(rb_.x), bf16_bits(rb_.y), bf16_bits(rb_.z), bf16_bits(rb_.w)}; \
        bf16x8 afrag = *(const bf16x8*)af_; \
        _Pragma("unroll") \
        for (int tt = 0; tt < 8; ++tt) { \
            bf16x8 bfr = *(const bf16x8*)&Bsh[(tt * 16 + l15) * 136 + s * 32 + l4 * 8]; \
            acc[tt] = __builtin_amdgcn_mfma_f32_16x16x32_bf16(bfr, afrag, acc[tt], 0, 0, 0); \
        } \
    } \
    const int row_ = (t) * 16 + l15; \
    _Pragma("unroll") \
    for (int tt = 0; tt < 8; ++tt) { \
        float hadd_[4] = {bits_to_f((ushort_t)(hv[tt].x & 0xffff)), \
                          bits_to_f((ushort_t)(hv[tt].x >> 16)), \
                          bits_to_f((ushort_t)(hv[tt].y & 0xffff)), \
                          bits_to_f((ushort_t)(hv[tt].y >> 16))}; \
        ushort_t o_[4]; \
        _Pragma("unroll") \
        for (int j = 0; j < 4; ++j) { \
            float v_ = acc[tt][j] + hadd_[j]; \
            lsum += v_; lsq += v_ * v_; \
            o_[j] = bf16_bits(v_); \
        } \
        *(uint2*)&e0[(size_t)row_ * DD + tt * 16 + l4 * 4] = *(const uint2*)o_; \
    } }

__global__ __launch_bounds__(256) void k4_gemm2(
    const float* __restrict__ ef, const ushort_t* __restrict__ hh,
    const int* __restrict__ eidx, const float* __restrict__ W2,
    ushort_t* __restrict__ e0, u64* __restrict__ stats, int nblocks)
{
    __shared__ bf16 Bsh[128 * 136];
    __shared__ float red[256];
    const int tid = threadIdx.x;
    const int lane = tid & 63;
    const int w = tid >> 6;
    const int l15 = lane & 15, l4 = lane >> 4;

    {
        int n = tid & 127;
        int kb0 = (tid >> 7) * 8;
        #pragma unroll
        for (int i = 0; i < 8; ++i) {
            int kb = kb0 + i;
            ushort_t o[8];
            #pragma unroll
            for (int j = 0; j < 8; ++j)
                o[j] = bf16_bits(W2[(size_t)(kb * 8 + j) * DD + n]);
            *(uint4*)&Bsh[n * 136 + kb * 8] = *(const uint4*)o;
        }
    }
    __syncthreads();

    float lsum = 0.f, lsq = 0.f;
    const int S = nblocks * 4;

    float4 rA0, rA1, rA2, rA3, rA4, rA5, rA6, rA7;
    float4 rB0, rB1, rB2, rB3, rB4, rB5, rB6, rB7;
    #define rA_arr(i) (i==0?rA0:i==1?rA1:i==2?rA2:i==3?rA3:i==4?rA4:i==5?rA5:i==6?rA6:rA7)
    #define rB_arr(i) (i==0?rB0:i==1?rB1:i==2?rB2:i==3?rB3:i==4?rB4:i==5?rB5:i==6?rB6:rB7)
    uint2 hvA[8], hvB[8];
    int srcA = 0, srcB = 0, srcC = 0;

    int g = blockIdx.x * 4 + w;
    K4_LOAD_SRC(srcA, g);
    K4_LOAD_PANEL(rA, g);
    K4_LOAD_SRC(srcB, g + S);
    K4_LOAD_HV(hvA, srcA, g);

    while (g < K4_WTILES) {
        {
            K4_LOAD_SRC(srcC, g + 2 * S);
            K4_LOAD_HV(hvB, srcB, g + S);
            K4_LOAD_PANEL(rB, g + S);
            K4_COMPUTE_STORE(g, rA, hvA);
        }
        g += S;
        if (g >= K4_WTILES) break;
        {
            K4_LOAD_SRC(srcB, g + 2 * S);
            K4_LOAD_HV(hvA, srcC, g + S);
            K4_LOAD_PANEL(rA, g + S);
            K4_COMPUTE_STORE(g, rB, hvB);
        }
        g += S;
    }
    stats_atomic(lsum, lsq, red, &stats[2], &stats[3]);
}

// ---------------- K7: bucket edges by dst ------------------------------------
__global__ __launch_bounds__(256) void k7_fill(
    const int* __restrict__ eidx, int* __restrict__ cnt, int* __restrict__ slot)
{
    int e = blockIdx.x * 256 + threadIdx.x;
    if (e >= N_EDGES) return;
    int dst = eidx[(size_t)e * 2 + 1];
    int pos = atomicAdd(&cnt[dst], 1);
    if (pos < MAXDEG) slot[dst * MAXDEG + pos] = e;
}

// ---------------- K8: per-node gather + norm + fast-gelu + mean --------------
// Quarter-wave per row: 16 lanes x uint4 = one 256B row per load; 4 rows per
// instruction, 8 rows (2KB) in flight per wave. Avg degree 6.4 -> usually one
// batched iteration (one latency round-trip per node).
__global__ __launch_bounds__(256) void k8_gather(
    const ushort_t* __restrict__ e0v, const int* __restrict__ slot,
    const int* __restrict__ cnt, const u64* __restrict__ stats,
    float* __restrict__ out)
{
    float mu, rs;
    stats_decode(stats + 2, (double)N_EDGES * DD, &mu, &rs);
    int node = (int)((blockIdx.x * 256 + threadIdx.x) >> 6);
    int lane = threadIdx.x & 63;
    if (node >= N_NODES) return;
    const int qw = lane >> 4;     // quarter-wave id: which row of the batch
    const int ql = lane & 15;     // col chunk (8 elems = 16 B)
    int c = cnt[node];
    int m = min(c, MAXDEG);
    int myslot = (lane < m) ? slot[node * MAXDEG + lane] : 0;
    float a[8] = {0.f, 0.f, 0.f, 0.f, 0.f, 0.f, 0.f, 0.f};
    const size_t off = (size_t)(ql * 8);

    for (int j = 0; j < m; j += 8) {
        int r0 = j + qw;
        int r1 = j + 4 + qw;
        int ei0 = __shfl(myslot, min(r0, m - 1));
        int ei1 = __shfl(myslot, min(r1, m - 1));
        uint4 u0 = *(const uint4*)&e0v[(size_t)ei0 * DD + off];
        uint4 u1 = *(const uint4*)&e0v[(size_t)ei1 * DD + off];
        if (r0 < m) {
            a[0] += gelu_fast((__uint_as_float(u0.x << 16) - mu) * rs);
            a[1] += gelu_fast((__uint_as_float(u0.x & 0xffff0000u) - mu) * rs);
            a[2] += gelu_fast((__uint_as_float(u0.y << 16) - mu) * rs);
            a[3] += gelu_fast((__uint_as_float(u0.y & 0xffff0000u) - mu) * rs);
            a[4] += gelu_fast((__uint_as_float(u0.z << 16) - mu) * rs);
            a[5] += gelu_fast((__uint_as_float(u0.z & 0xffff0000u) - mu) * rs);
            a[6] += gelu_fast((__uint_as_float(u0.w << 16) - mu) * rs);
            a[7] += gelu_fast((__uint_as_float(u0.w & 0xffff0000u) - mu) * rs);
        }
        if (r1 < m) {
            a[0] += gelu_fast((__uint_as_float(u1.x << 16) - mu) * rs);
            a[1] += gelu_fast((__uint_as_float(u1.x & 0xffff0000u) - mu) * rs);
            a[2] += gelu_fast((__uint_as_float(u1.y << 16) - mu) * rs);
            a[3] += gelu_fast((__uint_as_float(u1.y & 0xffff0000u) - mu) * rs);
            a[4] += gelu_fast((__uint_as_float(u1.z << 16) - mu) * rs);
            a[5] += gelu_fast((__uint_as_float(u1.z & 0xffff0000u) - mu) * rs);
            a[6] += gelu_fast((__uint_as_float(u1.w << 16) - mu) * rs);
            a[7] += gelu_fast((__uint_as_float(u1.w & 0xffff0000u) - mu) * rs);
        }
    }
    // rows are partitioned across quarter-waves: sum over qw
    #pragma unroll
    for (int i = 0; i < 8; ++i) {
        a[i] += __shfl_xor(a[i], 16);
        a[i] += __shfl_xor(a[i], 32);
    }
    if (qw == 0) {
        float inv = c > 0 ? 1.0f / (float)c : 0.f;
        float4 r0 = {a[0] * inv, a[1] * inv, a[2] * inv, a[3] * inv};
        float4 r1 = {a[4] * inv, a[5] * inv, a[6] * inv, a[7] * inv};
        *(float4*)&out[(size_t)node * DD + ql * 8] = r0;
        *(float4*)&out[(size_t)node * DD + ql * 8 + 4] = r1;
    }
}

// ---------------- launch -----------------------------------------------------
extern "C" void kernel_launch(void* const* d_in, const int* in_sizes, int n_in,
                              void* d_out, int out_size, void* d_ws, size_t ws_size,
                              hipStream_t stream) {
    const float* ef  = (const float*)d_in[0];
    const float* nf  = (const float*)d_in[1];
    const int*   eix = (const int*)d_in[2];
    const float* W1  = (const float*)d_in[3];
    const float* b1  = (const float*)d_in[4];
    const float* W2  = (const float*)d_in[5];
    const float* b2  = (const float*)d_in[6];
    float* out = (float*)d_out;
    char* ws = (char*)d_ws;

    ushort_t* hpre  = (ushort_t*)(ws + 0);           // 25,600,000
    ushort_t* hh    = (ushort_t*)(ws + 25600000);    // 25,600,000
    ushort_t* e0    = (ushort_t*)(ws + 51200000);    // 163,840,000
    int*      cnt   = (int*)(ws + 215040000);        // 400,000
    u64*      stats = (u64*)(ws + 215440000);        // 64 B
    int*      slot  = (int*)(ws + 215440064);        // 25,600,000

    k0_init<<<391, 256, 0, stream>>>(cnt, stats);
    k7_fill<<<2500, 256, 0, stream>>>(eix, cnt, slot);
    k1_gemm1<<<782, 256, 0, stream>>>(nf, W1, b1, hpre, stats, 782);
    k2b_gemmh<<<782, 256, 0, stream>>>(hpre, W2, b2, stats, hh, 782);
    k4_gemm2<<<1024, 256, 0, stream>>>(ef, hh, eix, W2, e0, stats, 1024);
    k8_gather<<<25000, 256, 0, stream>>>(e0, slot, cnt, stats, out);
}